// Round 2
// baseline (585.554 us; speedup 1.0000x reference)
//
#include <hip/hip_runtime.h>

typedef __bf16 bf16;
typedef __bf16 bf16x8 __attribute__((ext_vector_type(8)));
typedef __bf16 bf16x4 __attribute__((ext_vector_type(4)));
typedef float f32x4 __attribute__((ext_vector_type(4)));

constexpr int BB   = 8;
constexpr int LQ   = 2048;
constexpr int LKV  = 1024;
constexpr int DM   = 1024;   // H*DK
constexpr int DIMG = 512;
constexpr int H    = 16;
constexpr int DK   = 64;

__device__ inline void async16(const bf16* g, bf16* l) {
  __builtin_amdgcn_global_load_lds((const __attribute__((address_space(1))) void*)g,
                                   (__attribute__((address_space(3))) void*)l, 16, 0, 0);
}
__device__ inline float fexp2(float x) { return __builtin_amdgcn_exp2f(x); }

// ---------------- fp32 -> bf16 convert ----------------
__global__ __launch_bounds__(256) void cvt_f32_bf16(const float* __restrict__ in,
                                                    bf16* __restrict__ out, int n4) {
  int i = blockIdx.x * 256 + threadIdx.x;
  if (i < n4) {
    const float4 f = ((const float4*)in)[i];
    bf16x4 o;
    o[0] = (bf16)f.x; o[1] = (bf16)f.y; o[2] = (bf16)f.z; o[3] = (bf16)f.w;
    ((bf16x4*)out)[i] = o;
  }
}

// ------------- W [K,N] fp32 -> WT [N,K] bf16 -------------
__global__ __launch_bounds__(256) void transpose_w(const float* __restrict__ W,
                                                   bf16* __restrict__ WT, int K, int N) {
  __shared__ float tile[64][65];
  const int k0 = blockIdx.x * 64, n0 = blockIdx.y * 64;
  const int tx = threadIdx.x & 63, tg = threadIdx.x >> 6;
#pragma unroll
  for (int i = 0; i < 16; ++i) {
    int row = tg * 16 + i;
    tile[row][tx] = W[(size_t)(k0 + row) * N + n0 + tx];
  }
  __syncthreads();
#pragma unroll
  for (int i = 0; i < 16; ++i) {
    int nrow = tg * 16 + i;
    WT[(size_t)(n0 + nrow) * K + k0 + tx] = (bf16)tile[tx][nrow];
  }
}

// ------------- C[M,N] = A[M,K] @ Bt[N,K]^T + bias ; m97-style (global_load_lds) -------------
// VT_OUT: write bf16 output transposed per-head: Vt[b][h][dk][t] (LKV tokens per batch)
template <typename OutT, bool VT_OUT>
__global__ __launch_bounds__(256) void gemm_bt(const bf16* __restrict__ A,
                                               const bf16* __restrict__ Bt,
                                               const float* __restrict__ bias,
                                               OutT* __restrict__ C,
                                               int M, int N, int K) {
  __shared__ __align__(16) bf16 As[128 * 32];
  __shared__ __align__(16) bf16 Bs[128 * 32];

  const int tid = threadIdx.x, lane = tid & 63, wave = tid >> 6;
  const int bm = blockIdx.x, bn = blockIdx.y;
  const int wm = (wave & 1) * 64, wn = (wave >> 1) * 64;
  const int fm = lane & 15, quad = lane >> 4, fk8 = quad * 8;

  f32x4 acc[4][4];
#pragma unroll
  for (int i = 0; i < 4; ++i)
#pragma unroll
    for (int j = 0; j < 4; ++j) {
      f32x4 z = {0.f, 0.f, 0.f, 0.f};
      acc[i][j] = z;
    }

  // staging: wave w covers 16 rows; lane l -> row l>>2, col (l&3)*8 (forced LDS layout)
  const int srow = lane >> 2, scol = (lane & 3) * 8;
  const bf16* Ab = A + (size_t)(bm * 128) * K;
  const bf16* Bb = Bt + (size_t)(bn * 128) * K;
  const bf16* ag0 = Ab + (size_t)(wave * 16 + srow) * K + scol;
  const bf16* ag1 = ag0 + (size_t)64 * K;
  const bf16* bg0 = Bb + (size_t)(wave * 16 + srow) * K + scol;
  const bf16* bg1 = bg0 + (size_t)64 * K;
  bf16* la0 = &As[(wave * 16) * 32];
  bf16* la1 = &As[(64 + wave * 16) * 32];
  bf16* lb0 = &Bs[(wave * 16) * 32];
  bf16* lb1 = &Bs[(64 + wave * 16) * 32];

  for (int k0 = 0; k0 < K; k0 += 32) {
    async16(ag0 + k0, la0);
    async16(ag1 + k0, la1);
    async16(bg0 + k0, lb0);
    async16(bg1 + k0, lb1);
    __syncthreads();  // drains vmcnt (barrier semantics)
    bf16x8 af[4], bfr[4];
#pragma unroll
    for (int i = 0; i < 4; ++i)
      af[i] = *(const bf16x8*)&As[(wm + i * 16 + fm) * 32 + fk8];
#pragma unroll
    for (int j = 0; j < 4; ++j)
      bfr[j] = *(const bf16x8*)&Bs[(wn + j * 16 + fm) * 32 + fk8];
#pragma unroll
    for (int i = 0; i < 4; ++i)
#pragma unroll
      for (int j = 0; j < 4; ++j)
        acc[i][j] = __builtin_amdgcn_mfma_f32_16x16x32_bf16(af[i], bfr[j], acc[i][j], 0, 0, 0);
    __syncthreads();
  }

#pragma unroll
  for (int j = 0; j < 4; ++j) {
    const int col = bn * 128 + wn + j * 16 + fm;
    const float bv = bias[col];
    if constexpr (VT_OUT) {
      const int h = col >> 6, dk = col & 63;
#pragma unroll
      for (int i = 0; i < 4; ++i) {
        const int row = bm * 128 + wm + i * 16 + quad * 4;  // global token row (r=0)
        const int b = row >> 10, t = row & 1023;            // LKV = 1024
        bf16x4 o;
#pragma unroll
        for (int r = 0; r < 4; ++r) o[r] = (bf16)(acc[i][j][r] + bv);
        *(bf16x4*)&C[(((size_t)(b * H + h) * DK + dk) << 10) + t] = o;
      }
    } else {
#pragma unroll
      for (int i = 0; i < 4; ++i) {
#pragma unroll
        for (int r = 0; r < 4; ++r) {
          const int row = bm * 128 + wm + i * 16 + quad * 4 + r;
          C[(size_t)row * N + col] = (OutT)(acc[i][j][r] + bv);
        }
      }
    }
  }
}

// ------------- flash attention, S^T form, no barriers in kv loop -------------
// qh, kh: [B, L, H*DK] bf16 natural. vt: [B][H][DK][LKV] bf16. out: [B, LQ, H*DK].
__global__ __launch_bounds__(256, 3) void attn_kernel(const bf16* __restrict__ qh,
                                                      const bf16* __restrict__ kh,
                                                      const bf16* __restrict__ vt,
                                                      bf16* __restrict__ out) {
  constexpr int LDP = 88;  // 64 kv + 24 pad: row=176B (16B-aligned), 44-dword stride (2-way max)
  __shared__ __align__(16) bf16 Ps[2 * 4 * 32 * LDP];  // [parity][wave][q32][LDP]

  const int tid = threadIdx.x, lane = tid & 63, w = tid >> 6;
  const int fm = lane & 15, quad = lane >> 4, fk8 = quad * 8;
  const int qt = blockIdx.x, h = blockIdx.y, b = blockIdx.z;
  const int q0 = qt * 128;
  const float scale2 = 0.125f * 1.44269504f;  // 1/sqrt(dk) * log2(e)

  // Q fragments (B-operand: lane holds Q[q = w*32 + i*16 + fm][k = kg*32 + fk8 .. +7])
  const bf16* qbase = qh + ((size_t)(b * LQ) + q0 + w * 32) * DM + h * DK;
  bf16x8 qf[2][2];
#pragma unroll
  for (int i = 0; i < 2; ++i)
#pragma unroll
    for (int kg = 0; kg < 2; ++kg)
      qf[i][kg] = *(const bf16x8*)&qbase[(size_t)(i * 16 + fm) * DM + kg * 32 + fk8];

  const bf16* kbase = kh + (size_t)(b * LKV) * DM + h * DK;
  const bf16* vbase = vt + (size_t)(b * H + h) * DK * LKV;

  float row_m[2] = {-1e30f, -1e30f}, row_l[2] = {0.f, 0.f};
  f32x4 o_acc[2][4];
#pragma unroll
  for (int i = 0; i < 2; ++i)
#pragma unroll
    for (int jd = 0; jd < 4; ++jd) {
      f32x4 z = {0.f, 0.f, 0.f, 0.f};
      o_acc[i][jd] = z;
    }

  bf16* Pw = &Ps[w * 32 * LDP];

  for (int t = 0; t < LKV / 64; ++t) {
    // ---- S^T = K Q^T : A-frag from K natural rows, per-lane 16B global loads ----
    f32x4 s[4][2];
#pragma unroll
    for (int m = 0; m < 4; ++m)
#pragma unroll
      for (int i = 0; i < 2; ++i) {
        f32x4 z = {0.f, 0.f, 0.f, 0.f};
        s[m][i] = z;
      }
#pragma unroll
    for (int kg = 0; kg < 2; ++kg) {
#pragma unroll
      for (int m = 0; m < 4; ++m) {
        bf16x8 kf = *(const bf16x8*)&kbase[(size_t)(t * 64 + m * 16 + fm) * DM + kg * 32 + fk8];
#pragma unroll
        for (int i = 0; i < 2; ++i)
          s[m][i] = __builtin_amdgcn_mfma_f32_16x16x32_bf16(kf, qf[i][kg], s[m][i], 0, 0, 0);
      }
    }

    // ---- online softmax over kv for each q column (q = w*32 + i*16 + fm) ----
    float alpha[2];
#pragma unroll
    for (int i = 0; i < 2; ++i) {
      float mt = -1e30f;
#pragma unroll
      for (int m = 0; m < 4; ++m)
#pragma unroll
        for (int r = 0; r < 4; ++r) {
          s[m][i][r] *= scale2;
          mt = fmaxf(mt, s[m][i][r]);
        }
      mt = fmaxf(mt, __shfl_xor(mt, 16));
      mt = fmaxf(mt, __shfl_xor(mt, 32));
      const float nm = fmaxf(row_m[i], mt);
      alpha[i] = fexp2(row_m[i] - nm);
      row_m[i] = nm;
      float ps = 0.f;
#pragma unroll
      for (int m = 0; m < 4; ++m)
#pragma unroll
        for (int r = 0; r < 4; ++r) {
          const float p = fexp2(s[m][i][r] - nm);
          s[m][i][r] = p;
          ps += p;
        }
      ps += __shfl_xor(ps, 16);
      ps += __shfl_xor(ps, 32);
      row_l[i] = row_l[i] * alpha[i] + ps;
    }
    // rescale O accumulator (alpha indexed by q = i*16 + quad*4 + r -> fetch from lane quad*4+r)
#pragma unroll
    for (int i = 0; i < 2; ++i)
#pragma unroll
      for (int r = 0; r < 4; ++r) {
        const float a_o = __shfl(alpha[i], quad * 4 + r);
#pragma unroll
        for (int jd = 0; jd < 4; ++jd) o_acc[i][jd][r] *= a_o;
      }

    // ---- P: C-layout [kv][q] -> LDS [q][kv] via packed b64, wave-private ----
    bf16* Pb = Pw + ((t & 1) ? 4 * 32 * LDP : 0);
#pragma unroll
    for (int i = 0; i < 2; ++i)
#pragma unroll
      for (int m = 0; m < 4; ++m) {
        bf16x4 p4;
#pragma unroll
        for (int r = 0; r < 4; ++r) p4[r] = (bf16)s[m][i][r];
        *(bf16x4*)&Pb[(i * 16 + fm) * LDP + m * 16 + quad * 4] = p4;
      }

    // ---- O += P V : A-frag from LDS, B-frag (V^T rows) 16B direct from global ----
#pragma unroll
    for (int kg = 0; kg < 2; ++kg) {
      bf16x8 pf[2];
#pragma unroll
      for (int i = 0; i < 2; ++i)
        pf[i] = *(const bf16x8*)&Pb[(i * 16 + fm) * LDP + kg * 32 + fk8];
#pragma unroll
      for (int jd = 0; jd < 4; ++jd) {
        bf16x8 vf = *(const bf16x8*)&vbase[(size_t)(jd * 16 + fm) * LKV + t * 64 + kg * 32 + fk8];
#pragma unroll
        for (int i = 0; i < 2; ++i)
          o_acc[i][jd] = __builtin_amdgcn_mfma_f32_16x16x32_bf16(pf[i], vf, o_acc[i][jd], 0, 0, 0);
      }
    }
  }

  // ---- epilogue: normalize, store natural [B,LQ,H*DK] ----
  const float linv0 = 1.0f / row_l[0], linv1 = 1.0f / row_l[1];
  bf16* obase = out + ((size_t)(b * LQ) + q0 + w * 32) * DM + h * DK;
#pragma unroll
  for (int i = 0; i < 2; ++i) {
    const float li = i ? linv1 : linv0;
#pragma unroll
    for (int r = 0; r < 4; ++r) {
      const float lo = __shfl(li, quad * 4 + r);
#pragma unroll
      for (int jd = 0; jd < 4; ++jd)
        obase[(size_t)(i * 16 + quad * 4 + r) * DM + jd * 16 + fm] =
            (bf16)(o_acc[i][jd][r] * lo);
    }
  }
}

extern "C" void kernel_launch(void* const* d_in, const int* in_sizes, int n_in,
                              void* d_out, int out_size, void* d_ws, size_t ws_size,
                              hipStream_t stream) {
  const float* q  = (const float*)d_in[0];
  const float* k  = (const float*)d_in[1];
  const float* v  = (const float*)d_in[2];
  const float* Wq = (const float*)d_in[3];
  const float* bq = (const float*)d_in[4];
  const float* Wk = (const float*)d_in[5];
  const float* bk = (const float*)d_in[6];
  const float* Wv = (const float*)d_in[7];
  const float* bv = (const float*)d_in[8];
  const float* Wo = (const float*)d_in[9];
  const float* bo = (const float*)d_in[10];
  float* out = (float*)d_out;

  char* ws = (char*)d_ws;
  size_t off = 0;
  auto alloc = [&](size_t bytes) -> void* {
    void* p = ws + off;
    off += (bytes + 255) & ~(size_t)255;
    return p;
  };

  const size_t nq = (size_t)BB * LQ * DM;
  const size_t nk = (size_t)BB * LKV * DIMG;
  const size_t nqh = (size_t)BB * LQ * DM;
  const size_t nkh = (size_t)BB * LKV * DM;

  bf16* qbf = (bf16*)alloc(nq * 2);  // reused as attn_out after q-proj
  bf16* kbf = (bf16*)alloc(nk * 2);
  bf16* vbf = (bf16*)alloc(nk * 2);
  bf16* WqT = (bf16*)alloc((size_t)DM * DM * 2);
  bf16* WkT = (bf16*)alloc((size_t)DM * DIMG * 2);
  bf16* WvT = (bf16*)alloc((size_t)DM * DIMG * 2);
  bf16* WoT = (bf16*)alloc((size_t)DM * DM * 2);
  bf16* qh  = (bf16*)alloc(nqh * 2);
  bf16* kh  = (bf16*)alloc(nkh * 2);
  bf16* Vt  = (bf16*)alloc(nkh * 2);  // [B][H][DK][LKV]
  bf16* attn_out = qbf;

  cvt_f32_bf16<<<(int)(nq / 4 / 256), 256, 0, stream>>>(q, qbf, (int)(nq / 4));
  cvt_f32_bf16<<<(int)(nk / 4 / 256), 256, 0, stream>>>(k, kbf, (int)(nk / 4));
  cvt_f32_bf16<<<(int)(nk / 4 / 256), 256, 0, stream>>>(v, vbf, (int)(nk / 4));

  transpose_w<<<dim3(DM / 64, DM / 64), 256, 0, stream>>>(Wq, WqT, DM, DM);
  transpose_w<<<dim3(DIMG / 64, DM / 64), 256, 0, stream>>>(Wk, WkT, DIMG, DM);
  transpose_w<<<dim3(DIMG / 64, DM / 64), 256, 0, stream>>>(Wv, WvT, DIMG, DM);
  transpose_w<<<dim3(DM / 64, DM / 64), 256, 0, stream>>>(Wo, WoT, DM, DM);

  gemm_bt<bf16, false><<<dim3(BB * LQ / 128, DM / 128), 256, 0, stream>>>(
      qbf, WqT, bq, qh, BB * LQ, DM, DM);
  gemm_bt<bf16, false><<<dim3(BB * LKV / 128, DM / 128), 256, 0, stream>>>(
      kbf, WkT, bk, kh, BB * LKV, DM, DIMG);
  gemm_bt<bf16, true><<<dim3(BB * LKV / 128, DM / 128), 256, 0, stream>>>(
      vbf, WvT, bv, Vt, BB * LKV, DM, DIMG);

  attn_kernel<<<dim3(LQ / 128, H, BB), 256, 0, stream>>>(qh, kh, Vt, attn_out);

  gemm_bt<float, false><<<dim3(BB * LQ / 128, DM / 128), 256, 0, stream>>>(
      attn_out, WoT, bo, out, BB * LQ, DM, DM);
}

// Round 3
// 556.932 us; speedup vs baseline: 1.0514x; 1.0514x over previous
//
#include <hip/hip_runtime.h>

typedef __bf16 bf16;
typedef __bf16 bf16x8 __attribute__((ext_vector_type(8)));
typedef __bf16 bf16x4 __attribute__((ext_vector_type(4)));
typedef float f32x4 __attribute__((ext_vector_type(4)));

constexpr int BB   = 8;
constexpr int LQ   = 2048;
constexpr int LKV  = 1024;
constexpr int DM   = 1024;   // H*DK
constexpr int DIMG = 512;
constexpr int H    = 16;
constexpr int DK   = 64;

__device__ inline void async16(const bf16* g, bf16* l) {
  __builtin_amdgcn_global_load_lds((const __attribute__((address_space(1))) void*)g,
                                   (__attribute__((address_space(3))) void*)l, 16, 0, 0);
}
__device__ inline float fexp2(float x) { return __builtin_amdgcn_exp2f(x); }

// ---------------- fused fp32 -> bf16 convert for q,k,v ----------------
__global__ __launch_bounds__(256) void cvt_all(const float* __restrict__ q,
                                               const float* __restrict__ k,
                                               const float* __restrict__ v,
                                               bf16* __restrict__ qo,
                                               bf16* __restrict__ ko,
                                               bf16* __restrict__ vo,
                                               int nq4, int nk4) {
  int i = blockIdx.x * 256 + threadIdx.x;
  const float* in;
  bf16* out;
  int idx;
  if (i < nq4) { in = q; out = qo; idx = i; }
  else if (i < nq4 + nk4) { in = k; out = ko; idx = i - nq4; }
  else if (i < nq4 + 2 * nk4) { in = v; out = vo; idx = i - nq4 - nk4; }
  else return;
  const float4 f = ((const float4*)in)[idx];
  bf16x4 o;
  o[0] = (bf16)f.x; o[1] = (bf16)f.y; o[2] = (bf16)f.z; o[3] = (bf16)f.w;
  ((bf16x4*)out)[idx] = o;
}

// ------------- fused weight transposes: W [K,N] fp32 -> WT [N,K] bf16 -------------
__global__ __launch_bounds__(256) void transpose_all(const float* __restrict__ Wq,
                                                     const float* __restrict__ Wk,
                                                     const float* __restrict__ Wv,
                                                     const float* __restrict__ Wo,
                                                     bf16* __restrict__ WqT,
                                                     bf16* __restrict__ WkT,
                                                     bf16* __restrict__ WvT,
                                                     bf16* __restrict__ WoT) {
  const int z = blockIdx.z;
  const float* W;
  bf16* WT;
  int K;
  if (z == 0) { W = Wq; WT = WqT; K = DM; }
  else if (z == 1) { W = Wk; WT = WkT; K = DIMG; }
  else if (z == 2) { W = Wv; WT = WvT; K = DIMG; }
  else { W = Wo; WT = WoT; K = DM; }
  const int N = DM;
  if (blockIdx.x * 64 >= K) return;  // uniform early-out for the 512-row weights

  __shared__ float tile[64][65];
  const int k0 = blockIdx.x * 64, n0 = blockIdx.y * 64;
  const int tx = threadIdx.x & 63, tg = threadIdx.x >> 6;
#pragma unroll
  for (int i = 0; i < 16; ++i) {
    int row = tg * 16 + i;
    tile[row][tx] = W[(size_t)(k0 + row) * N + n0 + tx];
  }
  __syncthreads();
#pragma unroll
  for (int i = 0; i < 16; ++i) {
    int nrow = tg * 16 + i;
    WT[(size_t)(n0 + nrow) * K + k0 + tx] = (bf16)tile[tx][nrow];
  }
}

// ------------- C[M,N] = A[M,K] @ Bt[N,K]^T + bias ; m97-style (global_load_lds) -------------
// VT_OUT: write bf16 output transposed per-head: Vt[b][h][dk][t] (LKV tokens per batch)
template <typename OutT, bool VT_OUT>
__global__ __launch_bounds__(256) void gemm_bt(const bf16* __restrict__ A,
                                               const bf16* __restrict__ Bt,
                                               const float* __restrict__ bias,
                                               OutT* __restrict__ C,
                                               int M, int N, int K) {
  __shared__ __align__(16) bf16 As[128 * 32];
  __shared__ __align__(16) bf16 Bs[128 * 32];

  const int tid = threadIdx.x, lane = tid & 63, wave = tid >> 6;
  const int bm = blockIdx.x, bn = blockIdx.y;
  const int wm = (wave & 1) * 64, wn = (wave >> 1) * 64;
  const int fm = lane & 15, quad = lane >> 4, fk8 = quad * 8;

  f32x4 acc[4][4];
#pragma unroll
  for (int i = 0; i < 4; ++i)
#pragma unroll
    for (int j = 0; j < 4; ++j) {
      f32x4 z = {0.f, 0.f, 0.f, 0.f};
      acc[i][j] = z;
    }

  const int srow = lane >> 2, scol = (lane & 3) * 8;
  const bf16* Ab = A + (size_t)(bm * 128) * K;
  const bf16* Bb = Bt + (size_t)(bn * 128) * K;
  const bf16* ag0 = Ab + (size_t)(wave * 16 + srow) * K + scol;
  const bf16* ag1 = ag0 + (size_t)64 * K;
  const bf16* bg0 = Bb + (size_t)(wave * 16 + srow) * K + scol;
  const bf16* bg1 = bg0 + (size_t)64 * K;
  bf16* la0 = &As[(wave * 16) * 32];
  bf16* la1 = &As[(64 + wave * 16) * 32];
  bf16* lb0 = &Bs[(wave * 16) * 32];
  bf16* lb1 = &Bs[(64 + wave * 16) * 32];

  for (int k0 = 0; k0 < K; k0 += 32) {
    async16(ag0 + k0, la0);
    async16(ag1 + k0, la1);
    async16(bg0 + k0, lb0);
    async16(bg1 + k0, lb1);
    __syncthreads();
    bf16x8 af[4], bfr[4];
#pragma unroll
    for (int i = 0; i < 4; ++i)
      af[i] = *(const bf16x8*)&As[(wm + i * 16 + fm) * 32 + fk8];
#pragma unroll
    for (int j = 0; j < 4; ++j)
      bfr[j] = *(const bf16x8*)&Bs[(wn + j * 16 + fm) * 32 + fk8];
#pragma unroll
    for (int i = 0; i < 4; ++i)
#pragma unroll
      for (int j = 0; j < 4; ++j)
        acc[i][j] = __builtin_amdgcn_mfma_f32_16x16x32_bf16(af[i], bfr[j], acc[i][j], 0, 0, 0);
    __syncthreads();
  }

#pragma unroll
  for (int j = 0; j < 4; ++j) {
    const int col = bn * 128 + wn + j * 16 + fm;
    const float bv = bias[col];
    if constexpr (VT_OUT) {
      const int h = col >> 6, dk = col & 63;
#pragma unroll
      for (int i = 0; i < 4; ++i) {
        const int row = bm * 128 + wm + i * 16 + quad * 4;
        const int b = row >> 10, t = row & 1023;  // LKV = 1024
        bf16x4 o;
#pragma unroll
        for (int r = 0; r < 4; ++r) o[r] = (bf16)(acc[i][j][r] + bv);
        *(bf16x4*)&C[(((size_t)(b * H + h) * DK + dk) << 10) + t] = o;
      }
    } else {
#pragma unroll
      for (int i = 0; i < 4; ++i) {
#pragma unroll
        for (int r = 0; r < 4; ++r) {
          const int row = bm * 128 + wm + i * 16 + quad * 4 + r;
          C[(size_t)row * N + col] = (OutT)(acc[i][j][r] + bv);
        }
      }
    }
  }
}

// ------------- flash attention, S^T form, barrier-free, register-pipelined -------------
// qh, kh: [B, L, H*DK] bf16. vt: [B][H][DK][LKV] bf16. out: [B, LQ, H*DK].
__global__ __launch_bounds__(256, 2) void attn_kernel(const bf16* __restrict__ qh,
                                                      const bf16* __restrict__ kh,
                                                      const bf16* __restrict__ vt,
                                                      bf16* __restrict__ out) {
  constexpr int LDP = 88;  // 44-dword row stride: fm and fm+8 alias (2-way, free)
  __shared__ __align__(16) bf16 Ps[4 * 32 * LDP];  // single buffer, wave-private slices

  const int tid = threadIdx.x, lane = tid & 63, w = tid >> 6;
  const int fm = lane & 15, quad = lane >> 4, fk8 = quad * 8;
  const int qt = blockIdx.x, h = blockIdx.y, b = blockIdx.z;
  const int q0 = qt * 128;
  const float scale2 = 0.125f * 1.44269504f;  // 1/sqrt(dk) * log2(e)

  // Q fragments (B-operand): lane holds Q[q = w*32 + i*16 + fm][k = kg*32 + fk8..+7]
  const bf16* qbase = qh + ((size_t)(b * LQ) + q0 + w * 32) * DM + h * DK;
  bf16x8 qf[2][2];
#pragma unroll
  for (int i = 0; i < 2; ++i)
#pragma unroll
    for (int kg = 0; kg < 2; ++kg)
      qf[i][kg] = *(const bf16x8*)&qbase[(size_t)(i * 16 + fm) * DM + kg * 32 + fk8];

  const bf16* kbase = kh + (size_t)(b * LKV) * DM + h * DK;
  const bf16* vbase = vt + (size_t)(b * H + h) * DK * LKV;

  float row_m[2] = {-1e30f, -1e30f}, row_l[2] = {0.f, 0.f};
  f32x4 o_acc[2][4];
#pragma unroll
  for (int i = 0; i < 2; ++i)
#pragma unroll
    for (int jd = 0; jd < 4; ++jd) {
      f32x4 z = {0.f, 0.f, 0.f, 0.f};
      o_acc[i][jd] = z;
    }

  bf16* Pw = &Ps[w * 32 * LDP];

  // K fragment ping-pong: kf[parity][kg][m]
  bf16x8 kf[2][2][4];
#pragma unroll
  for (int kg = 0; kg < 2; ++kg)
#pragma unroll
    for (int m = 0; m < 4; ++m)
      kf[0][kg][m] = *(const bf16x8*)&kbase[(size_t)(m * 16 + fm) * DM + kg * 32 + fk8];

#pragma unroll 2
  for (int t = 0; t < LKV / 64; ++t) {
    const int cur = t & 1;

    // ---- issue V loads for tile t (consumed ~500 cyc later in PV) ----
    bf16x8 vf[2][4];
#pragma unroll
    for (int kg = 0; kg < 2; ++kg)
#pragma unroll
      for (int jd = 0; jd < 4; ++jd)
        vf[kg][jd] = *(const bf16x8*)&vbase[(size_t)(jd * 16 + fm) * LKV + t * 64 + kg * 32 + fk8];

    // ---- prefetch K fragments for tile t+1 (clamped tail; redundant last iter) ----
    const int tn = (t < LKV / 64 - 1) ? t + 1 : t;
#pragma unroll
    for (int kg = 0; kg < 2; ++kg)
#pragma unroll
      for (int m = 0; m < 4; ++m)
        kf[cur ^ 1][kg][m] =
            *(const bf16x8*)&kbase[(size_t)(tn * 64 + m * 16 + fm) * DM + kg * 32 + fk8];

    // ---- S^T = K Q^T on the prefetched kf[cur] ----
    f32x4 s[4][2];
#pragma unroll
    for (int m = 0; m < 4; ++m)
#pragma unroll
      for (int i = 0; i < 2; ++i) {
        f32x4 z = {0.f, 0.f, 0.f, 0.f};
        s[m][i] = z;
      }
#pragma unroll
    for (int kg = 0; kg < 2; ++kg)
#pragma unroll
      for (int m = 0; m < 4; ++m)
#pragma unroll
        for (int i = 0; i < 2; ++i)
          s[m][i] = __builtin_amdgcn_mfma_f32_16x16x32_bf16(kf[cur][kg][m], qf[i][kg], s[m][i], 0, 0, 0);

    // ---- online softmax over kv for each q column (q = w*32 + i*16 + fm) ----
    float alpha[2];
#pragma unroll
    for (int i = 0; i < 2; ++i) {
      float mt = -1e30f;
#pragma unroll
      for (int m = 0; m < 4; ++m)
#pragma unroll
        for (int r = 0; r < 4; ++r) {
          s[m][i][r] *= scale2;
          mt = fmaxf(mt, s[m][i][r]);
        }
      mt = fmaxf(mt, __shfl_xor(mt, 16));
      mt = fmaxf(mt, __shfl_xor(mt, 32));
      const float nm = fmaxf(row_m[i], mt);
      alpha[i] = fexp2(row_m[i] - nm);
      row_m[i] = nm;
      float ps = 0.f;
#pragma unroll
      for (int m = 0; m < 4; ++m)
#pragma unroll
        for (int r = 0; r < 4; ++r) {
          const float p = fexp2(s[m][i][r] - nm);
          s[m][i][r] = p;
          ps += p;
        }
      ps += __shfl_xor(ps, 16);
      ps += __shfl_xor(ps, 32);
      row_l[i] = row_l[i] * alpha[i] + ps;
    }
#pragma unroll
    for (int i = 0; i < 2; ++i)
#pragma unroll
      for (int r = 0; r < 4; ++r) {
        const float a_o = __shfl(alpha[i], quad * 4 + r);
#pragma unroll
        for (int jd = 0; jd < 4; ++jd) o_acc[i][jd][r] *= a_o;
      }

    // ---- P: C-layout [kv][q] -> LDS [q][kv], packed b64, wave-private, in-order DS ----
#pragma unroll
    for (int i = 0; i < 2; ++i)
#pragma unroll
      for (int m = 0; m < 4; ++m) {
        bf16x4 p4;
#pragma unroll
        for (int r = 0; r < 4; ++r) p4[r] = (bf16)s[m][i][r];
        *(bf16x4*)&Pw[(i * 16 + fm) * LDP + m * 16 + quad * 4] = p4;
      }

    // ---- O += P V : A-frag from LDS, B-frag from registers (loaded at top) ----
#pragma unroll
    for (int kg = 0; kg < 2; ++kg) {
      bf16x8 pf[2];
#pragma unroll
      for (int i = 0; i < 2; ++i)
        pf[i] = *(const bf16x8*)&Pw[(i * 16 + fm) * LDP + kg * 32 + fk8];
#pragma unroll
      for (int jd = 0; jd < 4; ++jd)
#pragma unroll
        for (int i = 0; i < 2; ++i)
          o_acc[i][jd] = __builtin_amdgcn_mfma_f32_16x16x32_bf16(pf[i], vf[kg][jd], o_acc[i][jd], 0, 0, 0);
    }
  }

  // ---- epilogue: normalize, store natural [B,LQ,H*DK] ----
  const float linv0 = 1.0f / row_l[0], linv1 = 1.0f / row_l[1];
  bf16* obase = out + ((size_t)(b * LQ) + q0 + w * 32) * DM + h * DK;
#pragma unroll
  for (int i = 0; i < 2; ++i) {
    const float li = i ? linv1 : linv0;
#pragma unroll
    for (int r = 0; r < 4; ++r) {
      const float lo = __shfl(li, quad * 4 + r);
#pragma unroll
      for (int jd = 0; jd < 4; ++jd)
        obase[(size_t)(i * 16 + quad * 4 + r) * DM + jd * 16 + fm] =
            (bf16)(o_acc[i][jd][r] * lo);
    }
  }
}

extern "C" void kernel_launch(void* const* d_in, const int* in_sizes, int n_in,
                              void* d_out, int out_size, void* d_ws, size_t ws_size,
                              hipStream_t stream) {
  const float* q  = (const float*)d_in[0];
  const float* k  = (const float*)d_in[1];
  const float* v  = (const float*)d_in[2];
  const float* Wq = (const float*)d_in[3];
  const float* bq = (const float*)d_in[4];
  const float* Wk = (const float*)d_in[5];
  const float* bk = (const float*)d_in[6];
  const float* Wv = (const float*)d_in[7];
  const float* bv = (const float*)d_in[8];
  const float* Wo = (const float*)d_in[9];
  const float* bo = (const float*)d_in[10];
  float* out = (float*)d_out;

  char* ws = (char*)d_ws;
  size_t off = 0;
  auto alloc = [&](size_t bytes) -> void* {
    void* p = ws + off;
    off += (bytes + 255) & ~(size_t)255;
    return p;
  };

  const size_t nq = (size_t)BB * LQ * DM;
  const size_t nk = (size_t)BB * LKV * DIMG;
  const size_t nkh = (size_t)BB * LKV * DM;

  bf16* qbf = (bf16*)alloc(nq * 2);  // reused as attn_out after q-proj
  bf16* kbf = (bf16*)alloc(nk * 2);
  bf16* vbf = (bf16*)alloc(nk * 2);
  bf16* WqT = (bf16*)alloc((size_t)DM * DM * 2);
  bf16* WkT = (bf16*)alloc((size_t)DM * DIMG * 2);
  bf16* WvT = (bf16*)alloc((size_t)DM * DIMG * 2);
  bf16* WoT = (bf16*)alloc((size_t)DM * DM * 2);
  bf16* qh  = (bf16*)alloc(nq * 2);
  bf16* kh  = (bf16*)alloc(nkh * 2);
  bf16* Vt  = (bf16*)alloc(nkh * 2);  // [B][H][DK][LKV]
  bf16* attn_out = qbf;

  const int nq4 = (int)(nq / 4), nk4 = (int)(nk / 4);
  cvt_all<<<(nq4 + 2 * nk4 + 255) / 256, 256, 0, stream>>>(q, k, v, qbf, kbf, vbf, nq4, nk4);

  transpose_all<<<dim3(DM / 64, DM / 64, 4), 256, 0, stream>>>(Wq, Wk, Wv, Wo, WqT, WkT, WvT, WoT);

  gemm_bt<bf16, false><<<dim3(BB * LQ / 128, DM / 128), 256, 0, stream>>>(
      qbf, WqT, bq, qh, BB * LQ, DM, DM);
  gemm_bt<bf16, false><<<dim3(BB * LKV / 128, DM / 128), 256, 0, stream>>>(
      kbf, WkT, bk, kh, BB * LKV, DM, DIMG);
  gemm_bt<bf16, true><<<dim3(BB * LKV / 128, DM / 128), 256, 0, stream>>>(
      vbf, WvT, bv, Vt, BB * LKV, DM, DIMG);

  attn_kernel<<<dim3(LQ / 128, H, BB), 256, 0, stream>>>(qh, kh, Vt, attn_out);

  gemm_bt<float, false><<<dim3(BB * LQ / 128, DM / 128), 256, 0, stream>>>(
      attn_out, WoT, bo, out, BB * LQ, DM, DM);
}